// Round 4
// baseline (227.729 us; speedup 1.0000x reference)
//
#include <hip/hip_runtime.h>
#include <hip/hip_bf16.h>

#define NN 50000
#define EE 800000
#define FF 128
#define HH 128
#define HID2 64
#define TT 8
#define GG 64
#define MAXP 64         // max partial-blocks per group (group ~781 nodes / 32 per block ~ 25)
#define PADE 64         // padded edge slots per node (deg ~ Poisson(16); P(>=64) ~ 1e-20)
#define NPAD 50048      // NN padded to 64 (782 * 64)

using frag_ab = __attribute__((ext_vector_type(8))) short;  // 8 bf16
using frag_cd = __attribute__((ext_vector_type(4))) float;  // 4 fp32

__device__ inline unsigned short f2bf(float f) {
    union { float f; unsigned u; } v; v.f = f;
    unsigned r = v.u + 0x7fff + ((v.u >> 16) & 1);  // RNE
    return (unsigned short)(r >> 16);
}

// ---- K_INIT: W->Wt bf16  +  zero gsum/deg/gcnt  (1 launch, 196 blocks) ----
__global__ __launch_bounds__(256) void k_init(const float* __restrict__ W,
                                              unsigned short* __restrict__ wt_bf,
                                              float* __restrict__ gsum,
                                              int* __restrict__ deg,
                                              int* __restrict__ gcnt) {
    int t = threadIdx.x, blk = blockIdx.x;
    // job 1: W[k][c] -> wt_bf[c][k] (blocks 0..63)
    if (blk < 64) {
        int gid = blk * 256 + t;          // 16384 total
        int c = gid >> 7, k = gid & 127;
        wt_bf[gid] = f2bf(W[k * 128 + c]);
    }
    // job 2: zero gsum (blocks 64..95)
    if (blk >= 64 && blk < 96) {
        int gid = (blk - 64) * 256 + t;   // 8192 floats
        gsum[gid] = 0.f;
    }
    // job 3: zero gcnt (block 96)
    if (blk == 96 && t < GG) gcnt[t] = 0;
    // job 4: zero deg (all 196 blocks)
    int gid = blk * 256 + t;
    if (gid < NN) deg[gid] = 0;
}

// ---- K_SCAT: padded direct scatter — replaces the 5-kernel CSR build ------
// slot = atomicAdd(deg[dst]); srcs_pad[dst*64+slot] = src.
// deg doubles as the degree array for dinv = rsqrt(deg+1).
__global__ __launch_bounds__(256) void k_scat(const int* __restrict__ src,
                                              const int* __restrict__ dst,
                                              int* __restrict__ deg,
                                              int* __restrict__ srcs_pad) {
    int e = blockIdx.x * 256 + threadIdx.x;   // 3125 * 256 = EE exactly
    int d = dst[e];
    int slot = atomicAdd(&deg[d], 1);
    srcs_pad[(d << 6) + slot] = src[e];
}

// ---- K4: MFMA GEMM  hs = bf16( (x @ W) * dinv[row] ), direct fp32 x -------
// 64 rows/block, 4 waves; wave w -> rows [r0+16w, r0+16w+16). No LDS.
__global__ __launch_bounds__(256) void k_gemm(const float* __restrict__ x,
                                              const unsigned short* __restrict__ wt_bf,
                                              const int* __restrict__ deg,
                                              unsigned short* __restrict__ hs) {
    int tid = threadIdx.x;
    int w = tid >> 6, lane = tid & 63;
    int m = lane & 15, quad = lane >> 4;
    int r0 = blockIdx.x * 64 + w * 16;        // 782 blocks * 64 = NPAD exactly
    int row = r0 + m;
    frag_cd acc[8];
#pragma unroll
    for (int nt = 0; nt < 8; nt++) acc[nt] = frag_cd{0.f, 0.f, 0.f, 0.f};

#pragma unroll
    for (int k0 = 0; k0 < 128; k0 += 32) {
        unsigned short av[8];
        if (row < NN) {
            const float4* p = (const float4*)(x + (size_t)row * 128 + k0 + quad * 8);
            float4 a0 = p[0], a1 = p[1];
            av[0] = f2bf(a0.x); av[1] = f2bf(a0.y); av[2] = f2bf(a0.z); av[3] = f2bf(a0.w);
            av[4] = f2bf(a1.x); av[5] = f2bf(a1.y); av[6] = f2bf(a1.z); av[7] = f2bf(a1.w);
        } else {
#pragma unroll
            for (int j = 0; j < 8; j++) av[j] = 0;
        }
        frag_ab a = *(const frag_ab*)av;
#pragma unroll
        for (int nt = 0; nt < 8; nt++) {
            frag_ab bfr = *(const frag_ab*)(wt_bf + (size_t)(nt * 16 + m) * 128 + k0 + quad * 8);
            acc[nt] = __builtin_amdgcn_mfma_f32_16x16x32_bf16(a, bfr, acc[nt], 0, 0, 0);
        }
    }
#pragma unroll
    for (int reg = 0; reg < 4; reg++) {
        int gr = r0 + quad * 4 + reg;
        if (gr < NN) {
            float di = rsqrtf((float)deg[gr] + 1.0f);
#pragma unroll
            for (int nt = 0; nt < 8; nt++)
                hs[(size_t)gr * 128 + nt * 16 + m] = f2bf(acc[nt][reg] * di);
        }
    }
}

// ---------------- K5: gather + bias + relu + fused hierarchical pool -------
// Round-1 proven structure: 16 qwaves/block, 2 nodes/qwave (32 nodes/block),
// 8-deep gather pipeline. NEW: padded src lists (e = i*64, e1 = e+deg[i]) and
// atomic-free flush: block claims a slot via gcnt and writes its per-group
// partial non-atomically; k_head sums partials.
#define ACC8(u) \
    a0 += __uint_as_float((u).x << 16); a1 += __uint_as_float((u).x & 0xffff0000u); \
    a2 += __uint_as_float((u).y << 16); a3 += __uint_as_float((u).y & 0xffff0000u); \
    a4 += __uint_as_float((u).z << 16); a5 += __uint_as_float((u).z & 0xffff0000u); \
    a6 += __uint_as_float((u).w << 16); a7 += __uint_as_float((u).w & 0xffff0000u);

__global__ __launch_bounds__(256) void k_aggr(const uint4* __restrict__ hs4,
                                              const int* __restrict__ deg,
                                              const int* __restrict__ srcs,
                                              const float* __restrict__ bias,
                                              const int* __restrict__ batch,
                                              float* __restrict__ gsum,
                                              float* __restrict__ partials,
                                              int* __restrict__ gcnt) {
    __shared__ float gacc[8 * 128];   // 4 KB: 8 group slots (span>8 -> global)
    __shared__ int slotid[8];
    int tid = threadIdx.x;
    int qid = tid >> 4, sub = tid & 15;
    int i_base = blockIdx.x * 32;
    int g_first = batch[i_base];
    int last = i_base + 31; if (last >= NN) last = NN - 1;
    int gspan = batch[last] - g_first + 1;
    bool lds_pool = (gspan <= 8);
    int slots = lds_pool ? gspan : 0;
    for (int idx = tid; idx < slots * 128; idx += 256) gacc[idx] = 0.f;
    __syncthreads();

    const float4* b4 = (const float4*)(bias + sub * 8);
    float4 bb0 = b4[0], bb1 = b4[1];

    float racc[8];
#pragma unroll
    for (int j = 0; j < 8; j++) racc[j] = 0.f;
    int cur_lg = -1;

    for (int n = 0; n < 2; n++) {
        int i = i_base + qid * 2 + n;
        if (i >= NN) break;
        int lg = batch[i] - g_first;
        if (lg != cur_lg) {
            if (cur_lg >= 0) {
                float* gp = lds_pool ? &gacc[cur_lg * 128 + sub * 8]
                                     : &gsum[(g_first + cur_lg) * 128 + sub * 8];
#pragma unroll
                for (int j = 0; j < 8; j++) atomicAdd(&gp[j], racc[j]);
#pragma unroll
                for (int j = 0; j < 8; j++) racc[j] = 0.f;
            }
            cur_lg = lg;
        }
        int dg = deg[i];
        float di = rsqrtf((float)dg + 1.0f);
        uint4 su = hs4[(size_t)i * 16 + sub];
        float a0 = __uint_as_float(su.x << 16);
        float a1 = __uint_as_float(su.x & 0xffff0000u);
        float a2 = __uint_as_float(su.y << 16);
        float a3 = __uint_as_float(su.y & 0xffff0000u);
        float a4 = __uint_as_float(su.z << 16);
        float a5 = __uint_as_float(su.z & 0xffff0000u);
        float a6 = __uint_as_float(su.w << 16);
        float a7 = __uint_as_float(su.w & 0xffff0000u);
        int e = i << 6, e1 = e + dg;
        for (; e + 7 < e1; e += 8) {
            int s0 = srcs[e],     s1 = srcs[e + 1], s2 = srcs[e + 2], s3 = srcs[e + 3];
            int s4 = srcs[e + 4], s5 = srcs[e + 5], s6 = srcs[e + 6], s7 = srcs[e + 7];
            uint4 u0 = hs4[(size_t)s0 * 16 + sub];
            uint4 u1 = hs4[(size_t)s1 * 16 + sub];
            uint4 u2 = hs4[(size_t)s2 * 16 + sub];
            uint4 u3 = hs4[(size_t)s3 * 16 + sub];
            uint4 u4 = hs4[(size_t)s4 * 16 + sub];
            uint4 u5 = hs4[(size_t)s5 * 16 + sub];
            uint4 u6 = hs4[(size_t)s6 * 16 + sub];
            uint4 u7 = hs4[(size_t)s7 * 16 + sub];
            ACC8(u0) ACC8(u1) ACC8(u2) ACC8(u3)
            ACC8(u4) ACC8(u5) ACC8(u6) ACC8(u7)
        }
        for (; e + 3 < e1; e += 4) {
            int s0 = srcs[e], s1 = srcs[e + 1], s2 = srcs[e + 2], s3 = srcs[e + 3];
            uint4 u0 = hs4[(size_t)s0 * 16 + sub];
            uint4 u1 = hs4[(size_t)s1 * 16 + sub];
            uint4 u2 = hs4[(size_t)s2 * 16 + sub];
            uint4 u3 = hs4[(size_t)s3 * 16 + sub];
            ACC8(u0) ACC8(u1) ACC8(u2) ACC8(u3)
        }
        for (; e < e1; ++e) {
            uint4 u0 = hs4[(size_t)srcs[e] * 16 + sub];
            ACC8(u0)
        }
        racc[0] += fmaxf(fmaf(a0, di, bb0.x), 0.f);
        racc[1] += fmaxf(fmaf(a1, di, bb0.y), 0.f);
        racc[2] += fmaxf(fmaf(a2, di, bb0.z), 0.f);
        racc[3] += fmaxf(fmaf(a3, di, bb0.w), 0.f);
        racc[4] += fmaxf(fmaf(a4, di, bb1.x), 0.f);
        racc[5] += fmaxf(fmaf(a5, di, bb1.y), 0.f);
        racc[6] += fmaxf(fmaf(a6, di, bb1.z), 0.f);
        racc[7] += fmaxf(fmaf(a7, di, bb1.w), 0.f);
    }
    if (cur_lg >= 0) {
        float* gp = lds_pool ? &gacc[cur_lg * 128 + sub * 8]
                             : &gsum[(g_first + cur_lg) * 128 + sub * 8];
#pragma unroll
        for (int j = 0; j < 8; j++) atomicAdd(&gp[j], racc[j]);
    }
    __syncthreads();
    // flush: claim one partial slot per local group (2-3 atomics/block total),
    // then plain stores. Fallback to gsum atomics only on slot overflow.
    if (lds_pool) {
        if (tid < slots) {
            int s = atomicAdd(&gcnt[g_first + tid], 1);
            slotid[tid] = (s < MAXP) ? s : -1;
        }
        __syncthreads();
        for (int idx = tid; idx < slots * 128; idx += 256) {
            int lg = idx >> 7, ch = idx & 127;
            int s = slotid[lg];
            float v = gacc[idx];
            if (s >= 0)
                partials[((size_t)(g_first + lg) * MAXP + s) * 128 + ch] = v;
            else if (v != 0.f)
                atomicAdd(&gsum[(g_first + lg) * 128 + ch], v);
        }
    }
}

__device__ inline int lbound(const int* __restrict__ a, int n, int key) {
    int lo = 0, hi = n;
    while (lo < hi) {
        int mid = (lo + hi) >> 1;
        if (a[mid] < key) lo = mid + 1;
        else hi = mid;
    }
    return lo;
}

// ---------------- K7: head (partial-sum, mean, fc1+relu, actor, critic) ----
__global__ __launch_bounds__(64) void k_head(const float* __restrict__ gsum,
                                             const float* __restrict__ partials,
                                             const int* __restrict__ gcnt,
                                             const int* __restrict__ batch,
                                             const float* __restrict__ fc1_w,
                                             const float* __restrict__ fc1_b,
                                             const float* __restrict__ actor_w,
                                             const float* __restrict__ actor_b,
                                             const float* __restrict__ critic_w,
                                             const float* __restrict__ critic_b,
                                             float* __restrict__ out) {
    __shared__ float gs[128];
    __shared__ float zs[64];
    __shared__ float ls[8], es[8];
    int g = blockIdx.x, t = threadIdx.x;
    int lo = lbound(batch, NN, g), hi = lbound(batch, NN, g + 1);
    float invc = 1.f / fmaxf((float)(hi - lo), 1.f);
    float s0 = gsum[g * 128 + t];
    float s1 = gsum[g * 128 + 64 + t];
    int cnt = gcnt[g]; if (cnt > MAXP) cnt = MAXP;
    const float* pp = partials + (size_t)g * MAXP * 128;
    for (int s = 0; s < cnt; s++) {
        s0 += pp[s * 128 + t];
        s1 += pp[s * 128 + 64 + t];
    }
    gs[t] = s0 * invc;
    gs[t + 64] = s1 * invc;
    __syncthreads();
    float z = fc1_b[t];
    for (int k = 0; k < 128; k++) z = fmaf(gs[k], fc1_w[k * 64 + t], z);
    zs[t] = fmaxf(z, 0.f);
    __syncthreads();
    if (t < 8) {
        float l = actor_b[t];
        for (int k = 0; k < 64; k++) l = fmaf(zs[k], actor_w[k * 8 + t], l);
        ls[t] = l;
    }
    __syncthreads();
    if (t < 8) {
        float m = ls[0];
#pragma unroll
        for (int j = 1; j < 8; j++) m = fmaxf(m, ls[j]);
        es[t] = expf(ls[t] - m);
    }
    __syncthreads();
    if (t < 8) {
        float ssum = 0.f;
#pragma unroll
        for (int j = 0; j < 8; j++) ssum += es[j];
        out[g * 8 + t] = es[t] / ssum;
    }
    if (t == 32) {
        float v = critic_b[0];
        for (int k = 0; k < 64; k++) v = fmaf(zs[k], critic_w[k], v);
        out[GG * TT + g] = v;
    }
}

extern "C" void kernel_launch(void* const* d_in, const int* in_sizes, int n_in,
                              void* d_out, int out_size, void* d_ws, size_t ws_size,
                              hipStream_t stream) {
    const float* x        = (const float*)d_in[0];
    const int*   ei       = (const int*)d_in[1];
    const int*   batch    = (const int*)d_in[2];
    const float* W        = (const float*)d_in[3];
    const float* b        = (const float*)d_in[4];
    const float* fc1_w    = (const float*)d_in[5];
    const float* fc1_b    = (const float*)d_in[6];
    const float* actor_w  = (const float*)d_in[7];
    const float* actor_b  = (const float*)d_in[8];
    const float* critic_w = (const float*)d_in[9];
    const float* critic_b = (const float*)d_in[10];
    float* out = (float*)d_out;

    char* ws = (char*)d_ws;
    size_t off = 0;
    unsigned short* hs    = (unsigned short*)(ws + off); off += (size_t)NN * 128 * 2 + 64;   // 12.8 MB
    unsigned short* wt_bf = (unsigned short*)(ws + off); off += (size_t)128 * 128 * 2;       // 32 KB
    int*   deg       = (int*)(ws + off);      off += (size_t)NN * 4 + 16;                    // 200 KB
    int*   srcs_pad  = (int*)(ws + off);      off += (size_t)NN * PADE * 4;                  // 12.8 MB
    float* partials  = (float*)(ws + off);    off += (size_t)GG * MAXP * 128 * 4;            // 2 MB
    int*   gcnt      = (int*)(ws + off);      off += (size_t)GG * 4 + 16;
    float* gsum      = (float*)(ws + off);    off += (size_t)GG * HH * 4;                    // 32 KB

    const int* src = ei;        // edge_index[0]
    const int* dst = ei + EE;   // edge_index[1]

    k_init<<<196, 256, 0, stream>>>(W, wt_bf, gsum, deg, gcnt);
    k_scat<<<EE / 256, 256, 0, stream>>>(src, dst, deg, srcs_pad);
    k_gemm<<<NPAD / 64, 256, 0, stream>>>(x, wt_bf, deg, hs);
    k_aggr<<<(NN + 31) / 32, 256, 0, stream>>>((const uint4*)hs, deg, srcs_pad,
                                               b, batch, gsum, partials, gcnt);
    k_head<<<GG, 64, 0, stream>>>(gsum, partials, gcnt, batch, fc1_w, fc1_b,
                                  actor_w, actor_b, critic_w, critic_b, out);
}